// Round 1
// baseline (784.230 us; speedup 1.0000x reference)
//
#include <hip/hip_runtime.h>
#include <hip/hip_bf16.h>

typedef __attribute__((ext_vector_type(8))) short short8;
typedef __attribute__((ext_vector_type(4))) float f32x4;
typedef unsigned short u16;

// round-to-nearest-even fp32 -> bf16
__device__ inline u16 f2bf(float f) {
    union { float f; unsigned u; } x{f};
    unsigned r = (x.u + 0x7fff + ((x.u >> 16) & 1)) >> 16;
    return (u16)r;
}

// ---------------- convert fp32 -> bf16 (elementwise, float4) ----------------
__global__ __launch_bounds__(256) void cvt_bf16(const float* __restrict__ in,
                                                u16* __restrict__ out, int n) {
    int i = (blockIdx.x * 256 + threadIdx.x) * 4;
    if (i >= n) return;
    float4 v = *(const float4*)&in[i];
    uint2 o;
    o.x = (unsigned)f2bf(v.x) | ((unsigned)f2bf(v.y) << 16);
    o.y = (unsigned)f2bf(v.z) | ((unsigned)f2bf(v.w) << 16);
    *(uint2*)&out[i] = o;
}

// ---------------- transpose + convert: W[K][N] fp32 -> Wt[N][K] bf16 --------
__global__ __launch_bounds__(256) void transpose_cvt(const float* __restrict__ W,
                                                     u16* __restrict__ Wt,
                                                     int K, int N) {
    __shared__ float tile[32][33];
    int n0 = blockIdx.x * 32, k0 = blockIdx.y * 32;
    int tx = threadIdx.x, ty = threadIdx.y; // block (32,8)
    for (int i = 0; i < 32; i += 8)
        tile[ty + i][tx] = W[(size_t)(k0 + ty + i) * N + n0 + tx];
    __syncthreads();
    for (int i = 0; i < 32; i += 8)
        Wt[(size_t)(n0 + ty + i) * K + k0 + tx] = f2bf(tile[tx][ty + i]);
}

// ---------------- GEMM: C[M][N] = A[M][K] @ Bt[N][K]^T + bias ---------------
// A, Bt bf16 row-major (k-contiguous). 128x128 block tile, BK=64, 4 waves 2x2.
#define BM 128
#define BN 128
#define BK 64
__global__ __launch_bounds__(256) void gemm_bt(const u16* __restrict__ A,
                                               const u16* __restrict__ Bt,
                                               const float* __restrict__ bias,
                                               void* __restrict__ C,
                                               int M, int N, int K, int c_is_f32) {
    __shared__ u16 As[BM][BK + 8];
    __shared__ u16 Bs[BN][BK + 8];
    int tid = threadIdx.x;
    int wave = tid >> 6, lane = tid & 63;
    int quad = lane >> 4, l16 = lane & 15;
    int wm = (wave >> 1) * 64, wn = (wave & 1) * 64;
    int m0 = blockIdx.x * BM, n0 = blockIdx.y * BN;

    f32x4 acc[4][4] = {};

    for (int k0 = 0; k0 < K; k0 += BK) {
        __syncthreads();
        // stage 128x64 A and B tiles: 1024 chunks of 16B each, 4 per thread
        for (int i = 0; i < 4; i++) {
            int c = tid + i * 256;
            int r = c >> 3, cc = c & 7;
            uint4 av = *(const uint4*)&A[(size_t)(m0 + r) * K + k0 + cc * 8];
            *(uint4*)&As[r][cc * 8] = av;
            uint4 bv = *(const uint4*)&Bt[(size_t)(n0 + r) * K + k0 + cc * 8];
            *(uint4*)&Bs[r][cc * 8] = bv;
        }
        __syncthreads();
        for (int ks = 0; ks < 2; ks++) {
            short8 af[4], bf[4];
            for (int i = 0; i < 4; i++)
                af[i] = *(short8*)&As[wm + i * 16 + l16][ks * 32 + quad * 8];
            for (int j = 0; j < 4; j++)
                bf[j] = *(short8*)&Bs[wn + j * 16 + l16][ks * 32 + quad * 8];
            for (int i = 0; i < 4; i++)
                for (int j = 0; j < 4; j++)
                    acc[i][j] = __builtin_amdgcn_mfma_f32_16x16x32_bf16(
                        af[i], bf[j], acc[i][j], 0, 0, 0);
        }
    }

    for (int i = 0; i < 4; i++)
        for (int j = 0; j < 4; j++) {
            int col = n0 + wn + j * 16 + l16;
            float bv = bias ? bias[col] : 0.f;
            for (int r = 0; r < 4; r++) {
                int row = m0 + wm + i * 16 + quad * 4 + r;
                float v = acc[i][j][r] + bv;
                if (c_is_f32)
                    ((float*)C)[(size_t)row * N + col] = v;
                else
                    ((u16*)C)[(size_t)row * N + col] = f2bf(v);
            }
        }
}

// ---------------- flash attention (causal), bf16 MFMA -----------------------
// qkv: [B*S][3*D] bf16 (q at col 0, k at D, v at 2D; head h at h*64)
// out: [B*S][D] bf16
__global__ __launch_bounds__(256) void attn_kernel(const u16* __restrict__ qkv,
                                                   u16* __restrict__ out,
                                                   int B, int S, int H) {
    const int dh = 64;
    const int D = H * dh;          // 1024
    const int stride = 3 * D;      // 3072
    int bh = blockIdx.y;
    int b = bh / H, h = bh % H;
    int qt = blockIdx.x;
    int tid = threadIdx.x;
    int wave = tid >> 6, lane = tid & 63;
    int quad = lane >> 4, l16 = lane & 15;

    __shared__ u16 Klds[32][72];
    __shared__ u16 Vt[64][40];       // V transposed: Vt[d][n]
    __shared__ u16 Plds[4][16][40];  // per-wave P tile

    const u16* Qp = qkv + (size_t)(b * S) * stride + h * dh;
    const u16* Kp = Qp + D;
    const u16* Vp = Qp + 2 * D;

    // Q fragments for this wave's 16 rows (A-layout)
    int qrow_frag = qt * 64 + wave * 16 + l16;
    short8 qf0 = *(const short8*)&Qp[(size_t)qrow_frag * stride + quad * 8];
    short8 qf1 = *(const short8*)&Qp[(size_t)qrow_frag * stride + 32 + quad * 8];

    f32x4 O[4] = {};
    float mrun[4], lrun[4];
    for (int r = 0; r < 4; r++) { mrun[r] = -INFINITY; lrun[r] = 0.f; }

    int ntiles = 2 * qt + 2;  // K-tiles of 32 covering k <= qt*64+63

    for (int kt = 0; kt < ntiles; kt++) {
        __syncthreads();
        // stage K tile (row-major) and V tile (transposed): 1 chunk per thread
        {
            int n = tid >> 3, cc = tid & 7;
            size_t grow = (size_t)(kt * 32 + n) * stride;
            uint4 kv = *(const uint4*)&Kp[grow + cc * 8];
            *(uint4*)&Klds[n][cc * 8] = kv;
            uint4 vv = *(const uint4*)&Vp[grow + cc * 8];
            u16 tmp[8];
            *(uint4*)tmp = vv;
            for (int j = 0; j < 8; j++) Vt[cc * 8 + j][n] = tmp[j];
        }
        __syncthreads();

        // scores = Q @ K^T for two 16-col blocks
        f32x4 s[2];
        for (int nb = 0; nb < 2; nb++) {
            short8 kf0 = *(short8*)&Klds[nb * 16 + l16][quad * 8];
            short8 kf1 = *(short8*)&Klds[nb * 16 + l16][32 + quad * 8];
            f32x4 t = {};
            t = __builtin_amdgcn_mfma_f32_16x16x32_bf16(qf0, kf0, t, 0, 0, 0);
            t = __builtin_amdgcn_mfma_f32_16x16x32_bf16(qf1, kf1, t, 0, 0, 0);
            s[nb] = t;
        }

        // causal mask + 1/sqrt(dh) scale (C-layout: row=quad*4+r, col=l16)
        int qrow_c = qt * 64 + wave * 16 + quad * 4;
        for (int nb = 0; nb < 2; nb++) {
            int kcol = kt * 32 + nb * 16 + l16;
            for (int r = 0; r < 4; r++) {
                float v = s[nb][r] * 0.125f;
                s[nb][r] = (kcol <= qrow_c + r) ? v : -INFINITY;
            }
        }

        // online softmax per row
        for (int r = 0; r < 4; r++) {
            float mx = fmaxf(s[0][r], s[1][r]);
            for (int off = 1; off < 16; off <<= 1)
                mx = fmaxf(mx, __shfl_xor(mx, off));
            float mnew = fmaxf(mrun[r], mx);
            float alpha = __expf(mrun[r] - mnew);
            float e0 = __expf(s[0][r] - mnew);
            float e1 = __expf(s[1][r] - mnew);
            float sum = e0 + e1;
            for (int off = 1; off < 16; off <<= 1)
                sum += __shfl_xor(sum, off);
            lrun[r] = lrun[r] * alpha + sum;
            mrun[r] = mnew;
            for (int d = 0; d < 4; d++) O[d][r] *= alpha;
            s[0][r] = e0;
            s[1][r] = e1;
        }

        // P (C-layout) -> LDS -> A-layout
        for (int r = 0; r < 4; r++) {
            Plds[wave][quad * 4 + r][l16] = f2bf(s[0][r]);
            Plds[wave][quad * 4 + r][16 + l16] = f2bf(s[1][r]);
        }
        __syncthreads();

        short8 pf = *(short8*)&Plds[wave][l16][quad * 8];
        for (int d = 0; d < 4; d++) {
            short8 vf = *(short8*)&Vt[d * 16 + l16][quad * 8];
            O[d] = __builtin_amdgcn_mfma_f32_16x16x32_bf16(pf, vf, O[d], 0, 0, 0);
        }
    }

    // epilogue: normalize and store bf16
    int orow = qt * 64 + wave * 16 + quad * 4;
    for (int d = 0; d < 4; d++) {
        int col = h * dh + d * 16 + l16;
        for (int r = 0; r < 4; r++) {
            float v = O[d][r] / lrun[r];
            out[(size_t)(b * S + orow + r) * D + col] = f2bf(v);
        }
    }
}

// ---------------------------------------------------------------------------
extern "C" void kernel_launch(void* const* d_in, const int* in_sizes, int n_in,
                              void* d_out, int out_size, void* d_ws, size_t ws_size,
                              hipStream_t stream) {
    const float* x     = (const float*)d_in[0];  // [2,2048,1024]
    const float* w_in  = (const float*)d_in[1];  // [1024,3072]
    const float* b_in  = (const float*)d_in[2];  // [3072]
    const float* w_out = (const float*)d_in[3];  // [1024,1024]
    const float* b_out = (const float*)d_in[4];  // [1024]

    const int Bsz = 2, S = 2048, D = 1024, H = 16;
    const int M = Bsz * S;       // 4096
    const int N1 = 3 * D;        // 3072

    u16* ws    = (u16*)d_ws;
    u16* Xb    = ws;                       // M*D        = 4194304
    u16* WtIn  = Xb + (size_t)M * D;       // N1*D       = 3145728
    u16* WtOut = WtIn + (size_t)N1 * D;    // D*D        = 1048576
    u16* qkvb  = WtOut + (size_t)D * D;    // M*N1       = 12582912
    u16* attnb = qkvb + (size_t)M * N1;    // M*D        = 4194304

    // 1. convert x to bf16
    cvt_bf16<<<(M * D) / 1024, 256, 0, stream>>>(x, Xb, M * D);
    // 2. transpose-convert weights
    transpose_cvt<<<dim3(N1 / 32, D / 32), dim3(32, 8), 0, stream>>>(w_in, WtIn, D, N1);
    transpose_cvt<<<dim3(D / 32, D / 32), dim3(32, 8), 0, stream>>>(w_out, WtOut, D, D);
    // 3. qkv = x @ w_in + b_in
    gemm_bt<<<dim3(M / BM, N1 / BN), 256, 0, stream>>>(Xb, WtIn, b_in, qkvb,
                                                       M, N1, D, 0);
    // 4. attention
    attn_kernel<<<dim3(S / 64, Bsz * H), 256, 0, stream>>>(qkvb, attnb, Bsz, S, H);
    // 5. out = attn @ w_out + b_out  (fp32 output)
    gemm_bt<<<dim3(M / BM, D / BN), 256, 0, stream>>>(attnb, WtOut, b_out, d_out,
                                                      M, D, D, 1);
}

// Round 2
// 373.273 us; speedup vs baseline: 2.1010x; 2.1010x over previous
//
#include <hip/hip_runtime.h>
#include <hip/hip_bf16.h>

typedef __attribute__((ext_vector_type(8))) short short8;
typedef __attribute__((ext_vector_type(4))) float f32x4;
typedef unsigned short u16;

// round-to-nearest-even fp32 -> bf16
__device__ inline u16 f2bf(float f) {
    union { float f; unsigned u; } x{f};
    unsigned r = (x.u + 0x7fff + ((x.u >> 16) & 1)) >> 16;
    return (u16)r;
}

// ---------------- convert fp32 -> bf16 (elementwise, float4) ----------------
__global__ __launch_bounds__(256) void cvt_bf16(const float* __restrict__ in,
                                                u16* __restrict__ out, int n) {
    int i = (blockIdx.x * 256 + threadIdx.x) * 4;
    if (i >= n) return;
    float4 v = *(const float4*)&in[i];
    uint2 o;
    o.x = (unsigned)f2bf(v.x) | ((unsigned)f2bf(v.y) << 16);
    o.y = (unsigned)f2bf(v.z) | ((unsigned)f2bf(v.w) << 16);
    *(uint2*)&out[i] = o;
}

// ---------------- transpose + convert: W[K][N] fp32 -> Wt[N][K] bf16 --------
__global__ __launch_bounds__(256) void transpose_cvt(const float* __restrict__ W,
                                                     u16* __restrict__ Wt,
                                                     int K, int N) {
    __shared__ float tile[32][33];
    int n0 = blockIdx.x * 32, k0 = blockIdx.y * 32;
    int tx = threadIdx.x, ty = threadIdx.y; // block (32,8)
    for (int i = 0; i < 32; i += 8)
        tile[ty + i][tx] = W[(size_t)(k0 + ty + i) * N + n0 + tx];
    __syncthreads();
    for (int i = 0; i < 32; i += 8)
        Wt[(size_t)(n0 + ty + i) * K + k0 + tx] = f2bf(tile[tx][ty + i]);
}

// ---------------- GEMM: C[M][N] = A[M][K] @ Bt[N][K]^T + bias ---------------
// A, Bt bf16 row-major (k-contiguous). 128x128 block tile, BK=64, 4 waves 2x2.
// 1-D grid with GROUP_M raster swizzle for L2 locality.
#define BM 128
#define BN 128
#define BK 64
__global__ __launch_bounds__(256) void gemm_bt(const u16* __restrict__ A,
                                               const u16* __restrict__ Bt,
                                               const float* __restrict__ bias,
                                               void* __restrict__ C,
                                               int M, int N, int K, int c_is_f32) {
    __shared__ u16 smem[2][BM][BK + 8];   // 36864 B; reused as epilogue buffer
    u16 (*As)[BK + 8] = smem[0];
    u16 (*Bs)[BK + 8] = smem[1];

    int tid = threadIdx.x;
    int wave = tid >> 6, lane = tid & 63;
    int quad = lane >> 4, l16 = lane & 15;
    int wm = (wave >> 1) * 64, wn = (wave & 1) * 64;

    // GROUP_M=8 swizzle: consecutive blocks share a band of 8 A-tiles
    int nm = M / BM, nn = N / BN;
    const int GM = 8;
    int per_group = GM * nn;
    int group = blockIdx.x / per_group;
    int rem = blockIdx.x % per_group;
    int first_m = group * GM;
    int gsz = (nm - first_m < GM) ? (nm - first_m) : GM;
    int m0 = (first_m + rem % gsz) * BM;
    int n0 = (rem / gsz) * BN;

    f32x4 acc[4][4] = {};

    for (int k0 = 0; k0 < K; k0 += BK) {
        __syncthreads();
        for (int i = 0; i < 4; i++) {
            int c = tid + i * 256;
            int r = c >> 3, cc = c & 7;
            uint4 av = *(const uint4*)&A[(size_t)(m0 + r) * K + k0 + cc * 8];
            *(uint4*)&As[r][cc * 8] = av;
            uint4 bv = *(const uint4*)&Bt[(size_t)(n0 + r) * K + k0 + cc * 8];
            *(uint4*)&Bs[r][cc * 8] = bv;
        }
        __syncthreads();
        for (int ks = 0; ks < 2; ks++) {
            short8 af[4], bf[4];
            for (int i = 0; i < 4; i++)
                af[i] = *(short8*)&As[wm + i * 16 + l16][ks * 32 + quad * 8];
            for (int j = 0; j < 4; j++)
                bf[j] = *(short8*)&Bs[wn + j * 16 + l16][ks * 32 + quad * 8];
            for (int i = 0; i < 4; i++)
                for (int j = 0; j < 4; j++)
                    acc[i][j] = __builtin_amdgcn_mfma_f32_16x16x32_bf16(
                        af[i], bf[j], acc[i][j], 0, 0, 0);
        }
    }

    if (c_is_f32) {
        // f32 stores: 16 lanes x 4B = 64B full-line contiguous per quad-row
        for (int i = 0; i < 4; i++)
            for (int j = 0; j < 4; j++) {
                int col = n0 + wn + j * 16 + l16;
                float bv = bias ? bias[col] : 0.f;
                for (int r = 0; r < 4; r++) {
                    int row = m0 + wm + i * 16 + quad * 4 + r;
                    ((float*)C)[(size_t)row * N + col] = acc[i][j][r] + bv;
                }
            }
    } else {
        // bf16: repack through LDS, then 16B/lane coalesced stores
        __syncthreads();  // k-loop LDS reads done before overwrite
        u16 (*buf)[136] = (u16(*)[136])smem;  // 128x136 u16 = 34816 B
        for (int i = 0; i < 4; i++)
            for (int j = 0; j < 4; j++) {
                int col = wn + j * 16 + l16;
                float bv = bias ? bias[n0 + col] : 0.f;
                for (int r = 0; r < 4; r++)
                    buf[wm + i * 16 + quad * 4 + r][col] = f2bf(acc[i][j][r] + bv);
            }
        __syncthreads();
        u16* Cb = (u16*)C;
        for (int it = 0; it < 8; it++) {
            int c = tid + it * 256;            // 2048 chunks of 16B
            int row = c >> 4, k8 = c & 15;
            uint4 v = *(uint4*)&buf[row][k8 * 8];
            *(uint4*)&Cb[(size_t)(m0 + row) * N + n0 + k8 * 8] = v;
        }
    }
}

// ---------------- flash attention (causal), bf16 MFMA -----------------------
__global__ __launch_bounds__(256) void attn_kernel(const u16* __restrict__ qkv,
                                                   u16* __restrict__ out,
                                                   int B, int S, int H) {
    const int dh = 64;
    const int D = H * dh;          // 1024
    const int stride = 3 * D;      // 3072
    int bh = blockIdx.y;
    int b = bh / H, h = bh % H;
    int qt = blockIdx.x;
    int tid = threadIdx.x;
    int wave = tid >> 6, lane = tid & 63;
    int quad = lane >> 4, l16 = lane & 15;

    __shared__ u16 Klds[32][72];
    __shared__ u16 Vt[64][40];       // V transposed: Vt[d][n]
    __shared__ u16 Plds[4][16][40];  // per-wave P tile
    __shared__ u16 Obuf[4][16][72];  // per-wave output repack

    const u16* Qp = qkv + (size_t)(b * S) * stride + h * dh;
    const u16* Kp = Qp + D;
    const u16* Vp = Qp + 2 * D;

    int qrow_frag = qt * 64 + wave * 16 + l16;
    short8 qf0 = *(const short8*)&Qp[(size_t)qrow_frag * stride + quad * 8];
    short8 qf1 = *(const short8*)&Qp[(size_t)qrow_frag * stride + 32 + quad * 8];

    f32x4 O[4] = {};
    float mrun[4], lrun[4];
    for (int r = 0; r < 4; r++) { mrun[r] = -INFINITY; lrun[r] = 0.f; }

    int ntiles = 2 * qt + 2;

    for (int kt = 0; kt < ntiles; kt++) {
        __syncthreads();
        {
            int n = tid >> 3, cc = tid & 7;
            size_t grow = (size_t)(kt * 32 + n) * stride;
            uint4 kv = *(const uint4*)&Kp[grow + cc * 8];
            *(uint4*)&Klds[n][cc * 8] = kv;
            uint4 vv = *(const uint4*)&Vp[grow + cc * 8];
            u16 tmp[8];
            *(uint4*)tmp = vv;
            for (int j = 0; j < 8; j++) Vt[cc * 8 + j][n] = tmp[j];
        }
        __syncthreads();

        f32x4 s[2];
        for (int nb = 0; nb < 2; nb++) {
            short8 kf0 = *(short8*)&Klds[nb * 16 + l16][quad * 8];
            short8 kf1 = *(short8*)&Klds[nb * 16 + l16][32 + quad * 8];
            f32x4 t = {};
            t = __builtin_amdgcn_mfma_f32_16x16x32_bf16(qf0, kf0, t, 0, 0, 0);
            t = __builtin_amdgcn_mfma_f32_16x16x32_bf16(qf1, kf1, t, 0, 0, 0);
            s[nb] = t;
        }

        int qrow_c = qt * 64 + wave * 16 + quad * 4;
        for (int nb = 0; nb < 2; nb++) {
            int kcol = kt * 32 + nb * 16 + l16;
            for (int r = 0; r < 4; r++) {
                float v = s[nb][r] * 0.125f;
                s[nb][r] = (kcol <= qrow_c + r) ? v : -INFINITY;
            }
        }

        for (int r = 0; r < 4; r++) {
            float mx = fmaxf(s[0][r], s[1][r]);
            for (int off = 1; off < 16; off <<= 1)
                mx = fmaxf(mx, __shfl_xor(mx, off));
            float mnew = fmaxf(mrun[r], mx);
            float alpha = __expf(mrun[r] - mnew);
            float e0 = __expf(s[0][r] - mnew);
            float e1 = __expf(s[1][r] - mnew);
            float sum = e0 + e1;
            for (int off = 1; off < 16; off <<= 1)
                sum += __shfl_xor(sum, off);
            lrun[r] = lrun[r] * alpha + sum;
            mrun[r] = mnew;
            for (int d = 0; d < 4; d++) O[d][r] *= alpha;
            s[0][r] = e0;
            s[1][r] = e1;
        }

        for (int r = 0; r < 4; r++) {
            Plds[wave][quad * 4 + r][l16] = f2bf(s[0][r]);
            Plds[wave][quad * 4 + r][16 + l16] = f2bf(s[1][r]);
        }
        __syncthreads();

        short8 pf = *(short8*)&Plds[wave][l16][quad * 8];
        for (int d = 0; d < 4; d++) {
            short8 vf = *(short8*)&Vt[d * 16 + l16][quad * 8];
            O[d] = __builtin_amdgcn_mfma_f32_16x16x32_bf16(pf, vf, O[d], 0, 0, 0);
        }
    }

    // epilogue: normalize, repack through LDS, coalesced 16B stores
    for (int d = 0; d < 4; d++)
        for (int r = 0; r < 4; r++)
            Obuf[wave][quad * 4 + r][d * 16 + l16] = f2bf(O[d][r] / lrun[r]);
    __syncthreads();
    for (int it = 0; it < 2; it++) {
        int c = lane + it * 64;           // wave-local: 128 chunks of 16B
        int row = c >> 3, k8 = c & 7;
        uint4 v = *(uint4*)&Obuf[wave][row][k8 * 8];
        *(uint4*)&out[(size_t)(b * S + qt * 64 + wave * 16 + row) * D + h * dh + k8 * 8] = v;
    }
}

// ---------------------------------------------------------------------------
extern "C" void kernel_launch(void* const* d_in, const int* in_sizes, int n_in,
                              void* d_out, int out_size, void* d_ws, size_t ws_size,
                              hipStream_t stream) {
    const float* x     = (const float*)d_in[0];
    const float* w_in  = (const float*)d_in[1];
    const float* b_in  = (const float*)d_in[2];
    const float* w_out = (const float*)d_in[3];
    const float* b_out = (const float*)d_in[4];

    const int Bsz = 2, S = 2048, D = 1024, H = 16;
    const int M = Bsz * S;       // 4096
    const int N1 = 3 * D;        // 3072

    u16* ws    = (u16*)d_ws;
    u16* Xb    = ws;
    u16* WtIn  = Xb + (size_t)M * D;
    u16* WtOut = WtIn + (size_t)N1 * D;
    u16* qkvb  = WtOut + (size_t)D * D;
    u16* attnb = qkvb + (size_t)M * N1;

    cvt_bf16<<<(M * D) / 1024, 256, 0, stream>>>(x, Xb, M * D);
    transpose_cvt<<<dim3(N1 / 32, D / 32), dim3(32, 8), 0, stream>>>(w_in, WtIn, D, N1);
    transpose_cvt<<<dim3(D / 32, D / 32), dim3(32, 8), 0, stream>>>(w_out, WtOut, D, D);
    gemm_bt<<<(M / BM) * (N1 / BN), 256, 0, stream>>>(Xb, WtIn, b_in, qkvb,
                                                      M, N1, D, 0);
    attn_kernel<<<dim3(S / 64, Bsz * H), 256, 0, stream>>>(qkvb, attnb, Bsz, S, H);
    gemm_bt<<<(M / BM) * (D / BN), 256, 0, stream>>>(attnb, WtOut, b_out, d_out,
                                                     M, D, D, 1);
}

// Round 3
// 257.359 us; speedup vs baseline: 3.0472x; 1.4504x over previous
//
#include <hip/hip_runtime.h>
#include <hip/hip_bf16.h>

typedef __attribute__((ext_vector_type(8))) short short8;
typedef __attribute__((ext_vector_type(4))) float f32x4;
typedef unsigned short u16;

// round-to-nearest-even fp32 -> bf16
__device__ inline u16 f2bf(float f) {
    union { float f; unsigned u; } x{f};
    unsigned r = (x.u + 0x7fff + ((x.u >> 16) & 1)) >> 16;
    return (u16)r;
}

// ---------------- convert fp32 -> bf16 (elementwise, float4) ----------------
__global__ __launch_bounds__(256) void cvt_bf16(const float* __restrict__ in,
                                                u16* __restrict__ out, int n) {
    int i = (blockIdx.x * 256 + threadIdx.x) * 4;
    if (i >= n) return;
    float4 v = *(const float4*)&in[i];
    uint2 o;
    o.x = (unsigned)f2bf(v.x) | ((unsigned)f2bf(v.y) << 16);
    o.y = (unsigned)f2bf(v.z) | ((unsigned)f2bf(v.w) << 16);
    *(uint2*)&out[i] = o;
}

// ---------------- transpose + convert: W[K][N] fp32 -> Wt[N][K] bf16 --------
__global__ __launch_bounds__(256) void transpose_cvt(const float* __restrict__ W,
                                                     u16* __restrict__ Wt,
                                                     int K, int N) {
    __shared__ float tile[32][33];
    int n0 = blockIdx.x * 32, k0 = blockIdx.y * 32;
    int tx = threadIdx.x, ty = threadIdx.y; // block (32,8)
    for (int i = 0; i < 32; i += 8)
        tile[ty + i][tx] = W[(size_t)(k0 + ty + i) * N + n0 + tx];
    __syncthreads();
    for (int i = 0; i < 32; i += 8)
        Wt[(size_t)(n0 + ty + i) * K + k0 + tx] = f2bf(tile[tx][ty + i]);
}

// ---------------- transpose V slice of qkv -> Vt[b,h,dh,S] bf16 -------------
__global__ __launch_bounds__(256) void transpose_v(const u16* __restrict__ qkv,
                                                   u16* __restrict__ VT) {
    __shared__ u16 t[32][33];
    int s0 = blockIdx.x * 32, d0 = blockIdx.y * 32, bh = blockIdx.z;
    int b = bh >> 4, h = bh & 15;
    int tx = threadIdx.x, ty = threadIdx.y; // block (32,8)
    const u16* Vp = qkv + (size_t)(b * 2048) * 3072 + 2048 + h * 64;
    for (int i = 0; i < 32; i += 8)
        t[ty + i][tx] = Vp[(size_t)(s0 + ty + i) * 3072 + d0 + tx];
    __syncthreads();
    u16* Vr = VT + (size_t)bh * 64 * 2048;
    for (int i = 0; i < 32; i += 8)
        Vr[(size_t)(d0 + ty + i) * 2048 + s0 + tx] = t[tx][ty + i];
}

// ---------------- GEMM: C[M][N] = A[M][K] @ Bt[N][K]^T + bias ---------------
#define BM 128
#define BN 128
#define BK 64
__global__ __launch_bounds__(256) void gemm_bt(const u16* __restrict__ A,
                                               const u16* __restrict__ Bt,
                                               const float* __restrict__ bias,
                                               void* __restrict__ C,
                                               int M, int N, int K, int c_is_f32) {
    __shared__ u16 smem[2][BM][BK + 8];
    u16 (*As)[BK + 8] = smem[0];
    u16 (*Bs)[BK + 8] = smem[1];

    int tid = threadIdx.x;
    int wave = tid >> 6, lane = tid & 63;
    int quad = lane >> 4, l16 = lane & 15;
    int wm = (wave >> 1) * 64, wn = (wave & 1) * 64;

    int nm = M / BM, nn = N / BN;
    const int GM = 8;
    int per_group = GM * nn;
    int group = blockIdx.x / per_group;
    int rem = blockIdx.x % per_group;
    int first_m = group * GM;
    int gsz = (nm - first_m < GM) ? (nm - first_m) : GM;
    int m0 = (first_m + rem % gsz) * BM;
    int n0 = (rem / gsz) * BN;

    f32x4 acc[4][4] = {};

    for (int k0 = 0; k0 < K; k0 += BK) {
        __syncthreads();
        for (int i = 0; i < 4; i++) {
            int c = tid + i * 256;
            int r = c >> 3, cc = c & 7;
            uint4 av = *(const uint4*)&A[(size_t)(m0 + r) * K + k0 + cc * 8];
            *(uint4*)&As[r][cc * 8] = av;
            uint4 bv = *(const uint4*)&Bt[(size_t)(n0 + r) * K + k0 + cc * 8];
            *(uint4*)&Bs[r][cc * 8] = bv;
        }
        __syncthreads();
        for (int ks = 0; ks < 2; ks++) {
            short8 af[4], bf[4];
            for (int i = 0; i < 4; i++)
                af[i] = *(short8*)&As[wm + i * 16 + l16][ks * 32 + quad * 8];
            for (int j = 0; j < 4; j++)
                bf[j] = *(short8*)&Bs[wn + j * 16 + l16][ks * 32 + quad * 8];
            for (int i = 0; i < 4; i++)
                for (int j = 0; j < 4; j++)
                    acc[i][j] = __builtin_amdgcn_mfma_f32_16x16x32_bf16(
                        af[i], bf[j], acc[i][j], 0, 0, 0);
        }
    }

    if (c_is_f32) {
        for (int i = 0; i < 4; i++)
            for (int j = 0; j < 4; j++) {
                int col = n0 + wn + j * 16 + l16;
                float bv = bias ? bias[col] : 0.f;
                for (int r = 0; r < 4; r++) {
                    int row = m0 + wm + i * 16 + quad * 4 + r;
                    ((float*)C)[(size_t)row * N + col] = acc[i][j][r] + bv;
                }
            }
    } else {
        __syncthreads();
        u16 (*buf)[136] = (u16(*)[136])smem;
        for (int i = 0; i < 4; i++)
            for (int j = 0; j < 4; j++) {
                int col = wn + j * 16 + l16;
                float bv = bias ? bias[n0 + col] : 0.f;
                for (int r = 0; r < 4; r++)
                    buf[wm + i * 16 + quad * 4 + r][col] = f2bf(acc[i][j][r] + bv);
            }
        __syncthreads();
        u16* Cb = (u16*)C;
        for (int it = 0; it < 8; it++) {
            int c = tid + it * 256;
            int row = c >> 4, k8 = c & 15;
            uint4 v = *(uint4*)&buf[row][k8 * 8];
            *(uint4*)&Cb[(size_t)(m0 + row) * N + n0 + k8 * 8] = v;
        }
    }
}

// ---------------- flash attention (causal), BQ=128, BKT=64 ------------------
// qkv: [B*S][3D] bf16 ; VT: [B*H][64][S] bf16 ; out: [B*S][D] bf16
__global__ __launch_bounds__(256) void attn_kernel(const u16* __restrict__ qkv,
                                                   const u16* __restrict__ VT,
                                                   u16* __restrict__ out) {
    const int S = 2048, D = 1024, stride = 3072;
    int idx = blockIdx.x;                 // 512 blocks
    int qt = 15 - (idx >> 5);             // longest workgroups first
    int bh = idx & 31;
    int b = bh >> 4, h = bh & 15;
    int tid = threadIdx.x;
    int wave = tid >> 6, lane = tid & 63;
    int quad = lane >> 4, l16 = lane & 15;

    __shared__ u16 Klds[64][72];          // [seq][dh]
    __shared__ u16 Vlds[64][72];          // [dh][seq]
    __shared__ u16 Plds[4][32][72];       // per-wave P / O repack

    const u16* Qp = qkv + (size_t)(b * S) * stride + h * 64;
    const u16* Kp = Qp + D;
    const u16* Vtp = VT + (size_t)bh * 64 * S;

    // Q fragments: this wave's 32 rows (2 frags x 2 k-halves)
    short8 qf[2][2];
    for (int f = 0; f < 2; f++) {
        int qrow = qt * 128 + wave * 32 + f * 16 + l16;
        qf[f][0] = *(const short8*)&Qp[(size_t)qrow * stride + quad * 8];
        qf[f][1] = *(const short8*)&Qp[(size_t)qrow * stride + 32 + quad * 8];
    }

    f32x4 O[2][4] = {};
    float mrun[2][4], lrun[2][4];
    for (int f = 0; f < 2; f++)
        for (int r = 0; r < 4; r++) { mrun[f][r] = -INFINITY; lrun[f][r] = 0.f; }

    int ntiles = 2 * qt + 2;

    for (int kt = 0; kt < ntiles; kt++) {
        __syncthreads();
        // stage K[64][64] and V^T[64][64]: 512 chunks of 16B each, 2/thread
        for (int i = 0; i < 2; i++) {
            int c = tid + i * 256;
            int r = c >> 3, cc = c & 7;
            *(uint4*)&Klds[r][cc * 8] =
                *(const uint4*)&Kp[(size_t)(kt * 64 + r) * stride + cc * 8];
            *(uint4*)&Vlds[r][cc * 8] =
                *(const uint4*)&Vtp[(size_t)r * S + kt * 64 + cc * 8];
        }
        __syncthreads();

        // scores: s[f][nb] = Q(16 rows) @ K^T(16 cols)
        short8 kf[4][2];
        for (int nb = 0; nb < 4; nb++) {
            kf[nb][0] = *(short8*)&Klds[nb * 16 + l16][quad * 8];
            kf[nb][1] = *(short8*)&Klds[nb * 16 + l16][32 + quad * 8];
        }
        f32x4 s[2][4];
        for (int f = 0; f < 2; f++)
            for (int nb = 0; nb < 4; nb++) {
                f32x4 t = {};
                t = __builtin_amdgcn_mfma_f32_16x16x32_bf16(qf[f][0], kf[nb][0], t, 0, 0, 0);
                t = __builtin_amdgcn_mfma_f32_16x16x32_bf16(qf[f][1], kf[nb][1], t, 0, 0, 0);
                s[f][nb] = t;
            }

        // scale (+ causal mask only on the last two tiles)
        if (kt >= 2 * qt) {
            for (int f = 0; f < 2; f++) {
                int rbase = qt * 128 + wave * 32 + f * 16 + quad * 4;
                for (int nb = 0; nb < 4; nb++) {
                    int kcol = kt * 64 + nb * 16 + l16;
                    for (int r = 0; r < 4; r++) {
                        float v = s[f][nb][r] * 0.125f;
                        s[f][nb][r] = (kcol <= rbase + r) ? v : -INFINITY;
                    }
                }
            }
        } else {
            for (int f = 0; f < 2; f++)
                for (int nb = 0; nb < 4; nb++)
                    for (int r = 0; r < 4; r++)
                        s[f][nb][r] *= 0.125f;
        }

        // online softmax (reduction across l16 within quad; 64 cols at once)
        for (int f = 0; f < 2; f++)
            for (int r = 0; r < 4; r++) {
                float mx = fmaxf(fmaxf(s[f][0][r], s[f][1][r]),
                                 fmaxf(s[f][2][r], s[f][3][r]));
                for (int off = 1; off < 16; off <<= 1)
                    mx = fmaxf(mx, __shfl_xor(mx, off));
                float mnew = fmaxf(mrun[f][r], mx);
                float alpha = __expf(mrun[f][r] - mnew);
                float sum = 0.f;
                for (int nb = 0; nb < 4; nb++) {
                    float e = __expf(s[f][nb][r] - mnew);
                    s[f][nb][r] = e;
                    sum += e;
                }
                for (int off = 1; off < 16; off <<= 1)
                    sum += __shfl_xor(sum, off);
                lrun[f][r] = lrun[f][r] * alpha + sum;
                mrun[f][r] = mnew;
                for (int d = 0; d < 4; d++) O[f][d][r] *= alpha;
            }

        // P (C-layout) -> per-wave LDS -> A-layout (no barrier: wave-private)
        for (int f = 0; f < 2; f++)
            for (int nb = 0; nb < 4; nb++)
                for (int r = 0; r < 4; r++)
                    Plds[wave][f * 16 + quad * 4 + r][nb * 16 + l16] = f2bf(s[f][nb][r]);
        __asm__ volatile("s_waitcnt lgkmcnt(0)" ::: "memory");

        short8 pf[2][2], vf[4][2];
        for (int f = 0; f < 2; f++)
            for (int kh = 0; kh < 2; kh++)
                pf[f][kh] = *(short8*)&Plds[wave][f * 16 + l16][kh * 32 + quad * 8];
        for (int d = 0; d < 4; d++)
            for (int kh = 0; kh < 2; kh++)
                vf[d][kh] = *(short8*)&Vlds[d * 16 + l16][kh * 32 + quad * 8];
        for (int f = 0; f < 2; f++)
            for (int d = 0; d < 4; d++) {
                O[f][d] = __builtin_amdgcn_mfma_f32_16x16x32_bf16(pf[f][0], vf[d][0], O[f][d], 0, 0, 0);
                O[f][d] = __builtin_amdgcn_mfma_f32_16x16x32_bf16(pf[f][1], vf[d][1], O[f][d], 0, 0, 0);
            }
    }

    // epilogue: normalize, repack via wave-private LDS, 16B coalesced stores
    for (int f = 0; f < 2; f++)
        for (int d = 0; d < 4; d++)
            for (int r = 0; r < 4; r++)
                Plds[wave][f * 16 + quad * 4 + r][d * 16 + l16] =
                    f2bf(O[f][d][r] / lrun[f][r]);
    __asm__ volatile("s_waitcnt lgkmcnt(0)" ::: "memory");
    for (int i = 0; i < 4; i++) {
        int c = i * 64 + lane;            // 256 chunks of 16B per wave
        int row = c >> 3, cc = c & 7;
        uint4 v = *(uint4*)&Plds[wave][row][cc * 8];
        int grow = qt * 128 + wave * 32 + row;
        *(uint4*)&out[(size_t)(b * S + grow) * D + h * 64 + cc * 8] = v;
    }
}

// ---------------------------------------------------------------------------
extern "C" void kernel_launch(void* const* d_in, const int* in_sizes, int n_in,
                              void* d_out, int out_size, void* d_ws, size_t ws_size,
                              hipStream_t stream) {
    const float* x     = (const float*)d_in[0];
    const float* w_in  = (const float*)d_in[1];
    const float* b_in  = (const float*)d_in[2];
    const float* w_out = (const float*)d_in[3];
    const float* b_out = (const float*)d_in[4];

    const int Bsz = 2, S = 2048, D = 1024, H = 16;
    const int M = Bsz * S;       // 4096
    const int N1 = 3 * D;        // 3072

    u16* ws    = (u16*)d_ws;
    u16* Xb    = ws;                       // M*D      (dead after gemm1)
    u16* WtIn  = Xb + (size_t)M * D;
    u16* WtOut = WtIn + (size_t)N1 * D;
    u16* qkvb  = WtOut + (size_t)D * D;
    u16* attnb = qkvb + (size_t)M * N1;
    u16* Vt    = Xb;                       // alias: Xb dead once gemm1 ran

    cvt_bf16<<<(M * D) / 1024, 256, 0, stream>>>(x, Xb, M * D);
    transpose_cvt<<<dim3(N1 / 32, D / 32), dim3(32, 8), 0, stream>>>(w_in, WtIn, D, N1);
    transpose_cvt<<<dim3(D / 32, D / 32), dim3(32, 8), 0, stream>>>(w_out, WtOut, D, D);
    gemm_bt<<<(M / BM) * (N1 / BN), 256, 0, stream>>>(Xb, WtIn, b_in, qkvb,
                                                      M, N1, D, 0);
    transpose_v<<<dim3(S / 32, 2, Bsz * H), dim3(32, 8), 0, stream>>>(qkvb, Vt);
    attn_kernel<<<16 * Bsz * H, 256, 0, stream>>>(qkvb, Vt, attnb);
    gemm_bt<<<(M / BM) * (D / BN), 256, 0, stream>>>(attnb, WtOut, b_out, d_out,
                                                     M, D, D, 1);
}